// Round 1
// baseline (23426.892 us; speedup 1.0000x reference)
//
#include <hip/hip_runtime.h>
#include <hip/hip_bf16.h>

// LSTM: B=64, S=512, D=512, H=1024, L=2, O=256
// d_in: 0:x[64,512,512] 1:h0[2,64,1024] 2:c0[2,64,1024] 3:Wx0[4096,512] 4:Wh0[4096,1024]
//       5:bx0[4096] 6:bh0[4096] 7:Wx1[4096,1024] 8:Wh1[4096,1024] 9:bx1[4096] 10:bh1[4096]
//       11:fcW[256,1024] 12:fcb[256]
// out: sigmoid(h1_final @ fcW^T + fcb) [64,256] fp32

namespace {
constexpr int Bn = 64, Sn = 512, Dn = 512, Hn = 1024, NGn = 4096, On = 256;
}

typedef unsigned short u16;
typedef float f32x4 __attribute__((ext_vector_type(4)));
typedef short s16x8 __attribute__((ext_vector_type(8)));

__device__ __forceinline__ u16 f2bf(float f) {
    unsigned int u = __float_as_uint(f);
    unsigned int r = (u + 0x7fffu + ((u >> 16) & 1u)) >> 16;
    return (u16)r;
}
__device__ __forceinline__ float bf2f(u16 b) {
    return __uint_as_float(((unsigned int)b) << 16);
}
__device__ __forceinline__ float sigmf(float x) { return 1.0f / (1.0f + __expf(-x)); }

// ---------------- prep: pack weights to bf16, combine biases, init state ----------------
__global__ void prep_kernel(const float* __restrict__ Wx0, const float* __restrict__ Wh0,
                            const float* __restrict__ bx0, const float* __restrict__ bh0,
                            const float* __restrict__ Wx1, const float* __restrict__ Wh1,
                            const float* __restrict__ bx1, const float* __restrict__ bh1,
                            const float* __restrict__ h0in, const float* __restrict__ c0in,
                            u16* __restrict__ Wc0, u16* __restrict__ Wc1,
                            float* __restrict__ b0, float* __restrict__ b1,
                            u16* __restrict__ h0buf, u16* __restrict__ h1buf,
                            float* __restrict__ c0, float* __restrict__ c1) {
    const int idx = blockIdx.x * 256 + threadIdx.x;
    const int stride = gridDim.x * 256;
    // Wc0: [4096][1536] = [Wx0 row | Wh0 row]
    for (int i = idx; i < NGn * 1536; i += stride) {
        int n = i / 1536, k = i - n * 1536;
        float v = (k < Dn) ? Wx0[n * Dn + k] : Wh0[n * Hn + (k - Dn)];
        Wc0[i] = f2bf(v);
    }
    // Wc1: [4096][2048] = [Wx1 row | Wh1 row]
    for (int i = idx; i < NGn * 2048; i += stride) {
        int n = i >> 11, k = i & 2047;
        float v = (k < Hn) ? Wx1[n * Hn + k] : Wh1[n * Hn + (k - Hn)];
        Wc1[i] = f2bf(v);
    }
    for (int i = idx; i < NGn; i += stride) {
        b0[i] = bx0[i] + bh0[i];
        b1[i] = bx1[i] + bh1[i];
    }
    // initial states: L0 reads h0buf[1] at p=0, L1 reads h1buf[0] at p=1
    for (int i = idx; i < Bn * Hn; i += stride) {
        h0buf[1 * Bn * Hn + i] = f2bf(h0in[i]);             // layer 0 initial h
        h1buf[0 * Bn * Hn + i] = f2bf(h0in[Bn * Hn + i]);   // layer 1 initial h
        c0[i] = c0in[i];
        c1[i] = c0in[Bn * Hn + i];
    }
}

// ---------------- one pipelined phase: WGs 0..63 -> layer0@t=p, WGs 64..127 -> layer1@t=p-1 ----
__global__ __launch_bounds__(256) void lstm_step(
    const float* __restrict__ x,
    const u16* __restrict__ Wc0, const u16* __restrict__ Wc1,
    const float* __restrict__ b0, const float* __restrict__ b1,
    u16* __restrict__ h0buf, u16* __restrict__ h1buf,
    float* __restrict__ c0, float* __restrict__ c1, int p) {
    const int tid = threadIdx.x;
    const int wg = blockIdx.x;
    const bool L1 = (wg >= 64);
    if (!L1 && p >= Sn) return;   // no layer-0 work in final phase
    if (L1 && p == 0) return;     // no layer-1 work in first phase

    const int K = L1 ? 2048 : 1536;
    const u16* __restrict__ W = L1 ? Wc1 : Wc0;
    const float* __restrict__ bias = L1 ? b1 : b0;
    float* __restrict__ cst = L1 ? c1 : c0;
    const int t = L1 ? (p - 1) : p;
    const int col0 = (wg & 63) * 16;

    u16* __restrict__ hw = (L1 ? h1buf : h0buf) + (size_t)(p & 1) * (Bn * Hn);
    // first-half A source (L0: h-prev of layer0 ; L1: h0 output at t=p-1)
    const u16* __restrict__ hA0 = h0buf + (size_t)((L1 ? (p - 1) : (p + 1)) & 1) * (Bn * Hn);
    // second-half A source for L1: h1 prev
    const u16* __restrict__ hA1 = h1buf + (size_t)((p + 1) & 1) * (Bn * Hn);

    __shared__ __align__(16) char smem[16384];  // A chunk [64][128] bf16  (reused as gates fp32 [4][64][16])
    short* __restrict__ As = (short*)smem;

    const int wid = tid >> 6;          // wave = gate index 0..3 (i,f,g,o)
    const int lane = tid & 63;
    const int ln15 = lane & 15, lhi = lane >> 4;
    const int nrow = wid * Hn + col0 + ln15;   // gate-matrix row (and bias index)
    const float bv = bias[nrow];
    f32x4 acc[4];
#pragma unroll
    for (int mi = 0; mi < 4; ++mi) acc[mi] = f32x4{bv, bv, bv, bv};

    const u16* __restrict__ wrow = W + (size_t)nrow * K;

    const int nchunk = K >> 7;  // K/128
    for (int ci = 0; ci < nchunk; ++ci) {
        const int kc0 = ci << 7;
        __syncthreads();
        // stage A[64 rows][128 k] as bf16 into LDS, 16B blocks XOR-swizzled: blk' = blk ^ (row&7)
#pragma unroll
        for (int bb = 0; bb < 4; ++bb) {
            const int blkid = tid + bb * 256;   // 0..1023
            const int row = blkid >> 4;
            const int cb = blkid & 15;
            const int kg = kc0 + cb * 8;
            short stv[8];
            if (!L1) {
                if (kg < Dn) {
                    const float* src = x + ((size_t)row * Sn + t) * Dn + kg;
                    const float4 v0 = *(const float4*)(src);
                    const float4 v1 = *(const float4*)(src + 4);
                    stv[0] = (short)f2bf(v0.x); stv[1] = (short)f2bf(v0.y);
                    stv[2] = (short)f2bf(v0.z); stv[3] = (short)f2bf(v0.w);
                    stv[4] = (short)f2bf(v1.x); stv[5] = (short)f2bf(v1.y);
                    stv[6] = (short)f2bf(v1.z); stv[7] = (short)f2bf(v1.w);
                } else {
                    *(s16x8*)stv = *(const s16x8*)&hA0[(size_t)row * Hn + (kg - Dn)];
                }
            } else {
                if (kg < Hn) {
                    *(s16x8*)stv = *(const s16x8*)&hA0[(size_t)row * Hn + kg];
                } else {
                    *(s16x8*)stv = *(const s16x8*)&hA1[(size_t)row * Hn + (kg - Hn)];
                }
            }
            *(s16x8*)&As[row * 128 + ((cb ^ (row & 7)) * 8)] = *(s16x8*)stv;
        }
        __syncthreads();
#pragma unroll
        for (int kk = 0; kk < 4; ++kk) {
            const s16x8 bfrag = *(const s16x8*)(wrow + kc0 + kk * 32 + lhi * 8);
#pragma unroll
            for (int mi = 0; mi < 4; ++mi) {
                const int row = mi * 16 + ln15;
                const int blk = kk * 4 + lhi;
                const s16x8 afrag = *(const s16x8*)&As[row * 128 + ((blk ^ (row & 7)) * 8)];
                acc[mi] = __builtin_amdgcn_mfma_f32_16x16x32_bf16(afrag, bfrag, acc[mi], 0, 0, 0);
            }
        }
    }

    // exchange gate tiles through LDS:  gates[gate][m][j]
    __syncthreads();
    float* __restrict__ gs = (float*)smem;
#pragma unroll
    for (int mi = 0; mi < 4; ++mi)
#pragma unroll
        for (int r = 0; r < 4; ++r)
            gs[(wid * 64 + mi * 16 + lhi * 4 + r) * 16 + ln15] = acc[mi][r];
    __syncthreads();

    // elementwise cell update: this WG exclusively owns h-cols [col0, col0+16)
    const int j = tid & 15, mb = tid >> 4;
#pragma unroll
    for (int rr = 0; rr < 4; ++rr) {
        const int m = rr * 16 + mb;
        const float ig = gs[(0 * 64 + m) * 16 + j];
        const float fg = gs[(1 * 64 + m) * 16 + j];
        const float gg = gs[(2 * 64 + m) * 16 + j];
        const float og = gs[(3 * 64 + m) * 16 + j];
        const int idx = m * Hn + col0 + j;
        const float cold = cst[idx];
        const float cn = sigmf(fg) * cold + sigmf(ig) * tanhf(gg);
        const float hn = sigmf(og) * tanhf(cn);
        cst[idx] = cn;
        hw[idx] = f2bf(hn);
    }
}

// ---------------- final FC + sigmoid ----------------
__global__ __launch_bounds__(256) void fc_out(const u16* __restrict__ h1,
                                              const float* __restrict__ fcW,
                                              const float* __restrict__ fcb,
                                              float* __restrict__ out) {
    const int b = blockIdx.x;  // 64
    __shared__ float hs[Hn];
    for (int k = threadIdx.x; k < Hn; k += 256) hs[k] = bf2f(h1[(size_t)b * Hn + k]);
    __syncthreads();
    const int o = threadIdx.x;  // 256
    float acc = fcb[o];
    const float4* wr = (const float4*)(fcW + (size_t)o * Hn);
    const float4* hv = (const float4*)hs;
#pragma unroll 8
    for (int k4 = 0; k4 < Hn / 4; ++k4) {
        const float4 w = wr[k4];
        const float4 h = hv[k4];
        acc += w.x * h.x + w.y * h.y + w.z * h.z + w.w * h.w;
    }
    out[(size_t)b * On + o] = sigmf(acc);
}

extern "C" void kernel_launch(void* const* d_in, const int* in_sizes, int n_in,
                              void* d_out, int out_size, void* d_ws, size_t ws_size,
                              hipStream_t stream) {
    (void)in_sizes; (void)n_in; (void)out_size; (void)ws_size;
    const float* x   = (const float*)d_in[0];
    const float* h0i = (const float*)d_in[1];
    const float* c0i = (const float*)d_in[2];
    const float* Wx0 = (const float*)d_in[3];
    const float* Wh0 = (const float*)d_in[4];
    const float* bx0 = (const float*)d_in[5];
    const float* bh0 = (const float*)d_in[6];
    const float* Wx1 = (const float*)d_in[7];
    const float* Wh1 = (const float*)d_in[8];
    const float* bx1 = (const float*)d_in[9];
    const float* bh1 = (const float*)d_in[10];
    const float* fcW = (const float*)d_in[11];
    const float* fcb = (const float*)d_in[12];
    float* out = (float*)d_out;

    char* ws = (char*)d_ws;
    // layout (bytes)
    u16* Wc0   = (u16*)(ws + 0);            // 4096*1536*2 = 12,582,912
    u16* Wc1   = (u16*)(ws + 12582912);     // 4096*2048*2 = 16,777,216
    float* b0  = (float*)(ws + 29360128);   // 16,384
    float* b1  = (float*)(ws + 29376512);   // 16,384
    u16* h0buf = (u16*)(ws + 29392896);     // 2*64*1024*2 = 262,144
    u16* h1buf = (u16*)(ws + 29655040);     // 262,144
    float* c0  = (float*)(ws + 29917184);   // 262,144
    float* c1  = (float*)(ws + 30179328);   // 262,144  -> total ~30.4 MB

    prep_kernel<<<1024, 256, 0, stream>>>(Wx0, Wh0, bx0, bh0, Wx1, Wh1, bx1, bh1,
                                          h0i, c0i, Wc0, Wc1, b0, b1, h0buf, h1buf, c0, c1);

    for (int p = 0; p <= Sn; ++p) {
        lstm_step<<<128, 256, 0, stream>>>(x, Wc0, Wc1, b0, b1, h0buf, h1buf, c0, c1, p);
    }

    fc_out<<<64, 256, 0, stream>>>(h1buf /* parity 0 holds t=511 */, fcW, fcb, out);
}

// Round 3
// 17769.760 us; speedup vs baseline: 1.3184x; 1.3184x over previous
//
#include <hip/hip_runtime.h>
#include <hip/hip_bf16.h>

// LSTM: B=64, S=512, D=512, H=1024, L=2, O=256
// Persistent PLAIN-LAUNCH kernel: 256 WGs (128 per layer, 8 h-cols each),
// weights register-resident, c-state register-resident, bounded grid barrier per phase.

namespace {
constexpr int Bn = 64, Sn = 512, Dn = 512, Hn = 1024, On = 256;
constexpr int BH = Bn * Hn;  // 65536
}

typedef unsigned short u16;
typedef unsigned int u32;
typedef float f32x4 __attribute__((ext_vector_type(4)));
typedef short s16x8 __attribute__((ext_vector_type(8)));

__device__ __forceinline__ u16 f2bf(float f) {
    unsigned int u = __float_as_uint(f);
    unsigned int r = (u + 0x7fffu + ((u >> 16) & 1u)) >> 16;
    return (u16)r;
}
__device__ __forceinline__ float bf2f(u16 b) {
    return __uint_as_float(((unsigned int)b) << 16);
}
__device__ __forceinline__ float sigmf(float x) { return 1.0f / (1.0f + __expf(-x)); }

__device__ __forceinline__ s16x8 cvt8(const float4 a, const float4 b) {
    s16x8 v;
    v[0] = (short)f2bf(a.x); v[1] = (short)f2bf(a.y); v[2] = (short)f2bf(a.z); v[3] = (short)f2bf(a.w);
    v[4] = (short)f2bf(b.x); v[5] = (short)f2bf(b.y); v[6] = (short)f2bf(b.z); v[7] = (short)f2bf(b.w);
    return v;
}

template <int I> struct IC { static constexpr int v = I; };
template <int N, int I = 0, typename F>
__device__ __forceinline__ void sfor(F&& f) {
    if constexpr (I < N) { f(IC<I>{}); sfor<N, I + 1, F>(static_cast<F&&>(f)); }
}

// ---------------- prep: pack weights into per-wave fragment order ----------------
// Wpk layout: (((wg*4 + wave)*(NC*2) + (c*2 + nt))*512 + lane*8 + j)
// value = W[row][k], row = (nt*2 + (pr>>3))*1024 + wg*8 + (pr&7), pr=lane&15,
// k = (c*4 + wave)*32 + (lane>>4)*8 + j.  L0: k<512 -> Wx0 else Wh0; L1: k<1024 -> Wx1 else Wh1.
__global__ void prep_kernel(const float* __restrict__ Wx0, const float* __restrict__ Wh0,
                            const float* __restrict__ bx0, const float* __restrict__ bh0,
                            const float* __restrict__ Wx1, const float* __restrict__ Wh1,
                            const float* __restrict__ bx1, const float* __restrict__ bh1,
                            const float* __restrict__ h0in,
                            u16* __restrict__ Wpk0, u16* __restrict__ Wpk1,
                            float* __restrict__ bcomb,
                            u16* __restrict__ h0buf, u16* __restrict__ h1buf,
                            unsigned* __restrict__ cnt) {
    const long long idx = (long long)blockIdx.x * 256 + threadIdx.x;
    const long long stride = (long long)gridDim.x * 256;
    if (idx == 0) *cnt = 0u;

    for (long long i = idx; i < 128LL * 4 * 24 * 512; i += stride) {
        const int j = (int)(i & 7);
        const int lane = (int)((i >> 3) & 63);
        const int f = (int)(i >> 9);
        const int nt = f & 1;
        const int q = f >> 1;
        const int c = q % 12, r = q / 12;
        const int wv = r & 3, wg = r >> 2;
        const int pr = lane & 15, lh = lane >> 4;
        const int row = (nt * 2 + (pr >> 3)) * 1024 + wg * 8 + (pr & 7);
        const int k = (c * 4 + wv) * 32 + lh * 8 + j;
        const float v = (k < 512) ? Wx0[(size_t)row * 512 + k] : Wh0[(size_t)row * 1024 + (k - 512)];
        Wpk0[i] = f2bf(v);
    }
    for (long long i = idx; i < 128LL * 4 * 32 * 512; i += stride) {
        const int j = (int)(i & 7);
        const int lane = (int)((i >> 3) & 63);
        const int f = (int)(i >> 9);
        const int nt = f & 1;
        const int q = f >> 1;
        const int c = q & 15, r = q >> 4;
        const int wv = r & 3, wg = r >> 2;
        const int pr = lane & 15, lh = lane >> 4;
        const int row = (nt * 2 + (pr >> 3)) * 1024 + wg * 8 + (pr & 7);
        const int k = (c * 4 + wv) * 32 + lh * 8 + j;
        const float v = (k < 1024) ? Wx1[(size_t)row * 1024 + k] : Wh1[(size_t)row * 1024 + (k - 1024)];
        Wpk1[i] = f2bf(v);
    }
    for (long long i = idx; i < 4096; i += stride) {
        bcomb[i] = bx0[i] + bh0[i];
        bcomb[4096 + i] = bx1[i] + bh1[i];
    }
    // initial h states live in parity-1 slots (first read uses parity (ph+1)&1 with ph=0 / ph=1)
    for (long long i = idx; i < BH; i += stride) {
        h0buf[BH + i] = f2bf(h0in[i]);
        h1buf[BH + i] = f2bf(h0in[BH + i]);
    }
}

// ---------------- bounded monotonic grid barrier (hang-proof) ----------------
// Returns through *sdead: once a timeout fires, all future barriers are skipped.
__device__ __forceinline__ void gbar(unsigned* cnt, unsigned tgt, int* sdead) {
    __syncthreads();   // also drains this WG's vmcnt (stores retired to L2)
    if (threadIdx.x == 0 && !*sdead) {
        __threadfence();                       // release: h writes device-visible
        atomicAdd(cnt, 1u);
        int guard = 0;
        while (__hip_atomic_load(cnt, __ATOMIC_RELAXED, __HIP_MEMORY_SCOPE_AGENT) < tgt) {
            __builtin_amdgcn_s_sleep(4);
            if (++guard > (1 << 16)) { *sdead = 1; break; }   // ~8ms cap, then latch
        }
        __threadfence();                       // acquire: invalidate stale cache lines
    }
    __syncthreads();
}

// ---------------- per-layer persistent loop ----------------
// NC = K/128 chunks (L0:12, L1:16); XC = chunks from first A source (L0: x -> 4, L1: h0 -> 8)
template <int NC, int XC, int LAYER>
__device__ __forceinline__ void run_layer(const float* __restrict__ x,
                                          const u16* __restrict__ Wpk,
                                          const float* __restrict__ bias,
                                          const float* __restrict__ c0in,
                                          u16* h0buf, u16* h1buf,
                                          unsigned* cnt, int wg, char* smem, int* sdead) {
    const int tid = threadIdx.x;
    const int wid = tid >> 6, lane = tid & 63;
    const int ln15 = lane & 15, lhi = lane >> 4;
    const int col0 = wg * 8;
    short* As = (short*)smem;     // 2 x [64][128] bf16 A-chunk double buffer (16KB each)
    float* Pf = (float*)smem;     // reused: partials [128][67] f32 (34304 B)
    const int m_u = tid & 63, cp_u = tid >> 6;

    // register-resident weights: NC*2 fragments of 16B per lane
    s16x8 wfr[NC * 2];
    const u16* wbase = Wpk + ((size_t)(wg * 4 + wid) * (NC * 2)) * 512 + lane * 8;
    sfor<NC * 2>([&](auto ff) { wfr[ff.v] = *(const s16x8*)(wbase + (size_t)ff.v * 512); });

    float bR[4][2];
#pragma unroll
    for (int g = 0; g < 4; ++g) {
        bR[g][0] = bias[g * 1024 + col0 + cp_u * 2 + 0];
        bR[g][1] = bias[g * 1024 + col0 + cp_u * 2 + 1];
    }
    float cr0 = c0in[(size_t)m_u * 1024 + col0 + cp_u * 2 + 0];
    float cr1 = c0in[(size_t)m_u * 1024 + col0 + cp_u * 2 + 1];

    for (int ph = 0; ph <= 512; ++ph) {
        const bool active = (LAYER == 0) ? (ph < 512) : (ph >= 1);
        if (active) {
            const int t = (LAYER == 0) ? ph : ph - 1;
            const u16* hA = h0buf + (size_t)((ph + 1) & 1) * BH;  // L0: h0 prev ; L1: h0 current-t
            const u16* hB = h1buf + (size_t)(ph & 1) * BH;        // L1 only: h1 prev
            u16* hw = (LAYER == 0) ? h0buf + (size_t)(ph & 1) * BH
                                   : h1buf + (size_t)((ph + 1) & 1) * BH;

            // ---- prologue: stage chunk 0 into buffer 0
            {
                float4 xr[4][2]; s16x8 hr[4];
#pragma unroll
                for (int bb = 0; bb < 4; ++bb) {
                    const int blkid = tid + bb * 256, row = blkid >> 4, cb = blkid & 15;
                    const int kg = cb * 8;
                    if constexpr (LAYER == 0) {
                        const float* sp = x + ((size_t)row * Sn + t) * Dn + kg;
                        xr[bb][0] = *(const float4*)sp; xr[bb][1] = *(const float4*)(sp + 4);
                    } else {
                        hr[bb] = *(const s16x8*)&hA[(size_t)row * Hn + kg];
                    }
                }
#pragma unroll
                for (int bb = 0; bb < 4; ++bb) {
                    const int blkid = tid + bb * 256, row = blkid >> 4, cb = blkid & 15;
                    s16x8 v;
                    if constexpr (LAYER == 0) v = cvt8(xr[bb][0], xr[bb][1]);
                    else v = hr[bb];
                    *(s16x8*)&As[row * 128 + ((cb ^ (row & 7)) * 8)] = v;
                }
            }
            __syncthreads();

            f32x4 acc[4][2];
#pragma unroll
            for (int mi = 0; mi < 4; ++mi) {
                acc[mi][0] = f32x4{0.f, 0.f, 0.f, 0.f};
                acc[mi][1] = f32x4{0.f, 0.f, 0.f, 0.f};
            }

            sfor<NC>([&](auto cc) {
                constexpr int c = cc.v;
                float4 xr[4][2]; s16x8 hr[4];
                // issue next chunk's global loads early (latency hides under MFMA)
                if constexpr (c + 1 < NC) {
                    constexpr int cn = c + 1;
#pragma unroll
                    for (int bb = 0; bb < 4; ++bb) {
                        const int blkid = tid + bb * 256, row = blkid >> 4, cb = blkid & 15;
                        const int kg = cn * 128 + cb * 8;
                        if constexpr (LAYER == 0) {
                            if constexpr (cn < XC) {
                                const float* sp = x + ((size_t)row * Sn + t) * Dn + kg;
                                xr[bb][0] = *(const float4*)sp; xr[bb][1] = *(const float4*)(sp + 4);
                            } else {
                                hr[bb] = *(const s16x8*)&hA[(size_t)row * Hn + (kg - XC * 128)];
                            }
                        } else {
                            if constexpr (cn < XC) hr[bb] = *(const s16x8*)&hA[(size_t)row * Hn + kg];
                            else hr[bb] = *(const s16x8*)&hB[(size_t)row * Hn + (kg - XC * 128)];
                        }
                    }
                }
                // compute chunk c: wave wid handles k-slice (c*4 + wid)
                const int ab = (c & 1) * 8192;
#pragma unroll
                for (int mi = 0; mi < 4; ++mi) {
                    const int arow = mi * 16 + ln15;
                    const s16x8 af =
                        *(const s16x8*)&As[ab + arow * 128 + (((wid * 4 + lhi) ^ (arow & 7)) * 8)];
                    acc[mi][0] = __builtin_amdgcn_mfma_f32_16x16x32_bf16(af, wfr[c * 2 + 0], acc[mi][0], 0, 0, 0);
                    acc[mi][1] = __builtin_amdgcn_mfma_f32_16x16x32_bf16(af, wfr[c * 2 + 1], acc[mi][1], 0, 0, 0);
                }
                // write next chunk into the other buffer
                if constexpr (c + 1 < NC) {
                    constexpr int cn = c + 1;
                    const int wb = (cn & 1) * 8192;
#pragma unroll
                    for (int bb = 0; bb < 4; ++bb) {
                        const int blkid = tid + bb * 256, row = blkid >> 4, cb = blkid & 15;
                        s16x8 v;
                        if constexpr (LAYER == 0 && (c + 1) < XC) v = cvt8(xr[bb][0], xr[bb][1]);
                        else v = hr[bb];
                        *(s16x8*)&As[wb + row * 128 + ((cb ^ (row & 7)) * 8)] = v;
                    }
                }
                __syncthreads();
            });

            // ---- cross-wave reduction: partial sums -> LDS (reuse A buffers)
#pragma unroll
            for (int mi = 0; mi < 4; ++mi)
#pragma unroll
                for (int nt = 0; nt < 2; ++nt)
#pragma unroll
                    for (int r = 0; r < 4; ++r) {
                        const int m = mi * 16 + lhi * 4 + r;
                        const int g = nt * 2 + (ln15 >> 3), col = ln15 & 7;
                        Pf[(size_t)((wid * 4 + g) * 8 + col) * 67 + m] = acc[mi][nt][r];
                    }
            __syncthreads();

            // ---- fused cell update: thread owns (m_u, cols col0+2cp_u .. +1)
            float sg[4][2];
#pragma unroll
            for (int g = 0; g < 4; ++g) { sg[g][0] = bR[g][0]; sg[g][1] = bR[g][1]; }
#pragma unroll
            for (int wv = 0; wv < 4; ++wv)
#pragma unroll
                for (int g = 0; g < 4; ++g) {
                    sg[g][0] += Pf[(size_t)(wv * 32 + g * 8 + cp_u * 2 + 0) * 67 + m_u];
                    sg[g][1] += Pf[(size_t)(wv * 32 + g * 8 + cp_u * 2 + 1) * 67 + m_u];
                }
            const float i0 = sigmf(sg[0][0]), f0 = sigmf(sg[1][0]), g0 = tanhf(sg[2][0]), o0 = sigmf(sg[3][0]);
            const float i1 = sigmf(sg[0][1]), f1 = sigmf(sg[1][1]), g1 = tanhf(sg[2][1]), o1 = sigmf(sg[3][1]);
            cr0 = f0 * cr0 + i0 * g0;
            cr1 = f1 * cr1 + i1 * g1;
            const u16 hb0 = f2bf(o0 * tanhf(cr0));
            const u16 hb1 = f2bf(o1 * tanhf(cr1));
            *(u32*)&hw[(size_t)m_u * Hn + col0 + cp_u * 2] = (u32)hb0 | ((u32)hb1 << 16);
        }
        if (ph < 512) gbar(cnt, (unsigned)(ph + 1) * 256u, sdead);
    }
}

__global__ __launch_bounds__(256, 1) void lstm_persist(const float* __restrict__ x,
                                                       const u16* __restrict__ Wpk0,
                                                       const u16* __restrict__ Wpk1,
                                                       const float* __restrict__ bias,
                                                       const float* __restrict__ c0in,
                                                       u16* h0buf, u16* h1buf, unsigned* cnt) {
    __shared__ __align__(16) char smem[34816];
    __shared__ int sdead;
    if (threadIdx.x == 0) sdead = 0;
    if (blockIdx.x < 128)
        run_layer<12, 4, 0>(x, Wpk0, bias, c0in, h0buf, h1buf, cnt, blockIdx.x, smem, &sdead);
    else
        run_layer<16, 8, 1>(x, Wpk1, bias + 4096, c0in + BH, h0buf, h1buf, cnt, blockIdx.x - 128, smem, &sdead);
}

// ---------------- final FC + sigmoid ----------------
__global__ __launch_bounds__(256) void fc_out(const u16* __restrict__ h1,
                                              const float* __restrict__ fcW,
                                              const float* __restrict__ fcb,
                                              float* __restrict__ out) {
    const int b = blockIdx.x;  // 64
    __shared__ float hs[Hn];
    for (int k = threadIdx.x; k < Hn; k += 256) hs[k] = bf2f(h1[(size_t)b * Hn + k]);
    __syncthreads();
    const int o = threadIdx.x;  // 256
    float acc = fcb[o];
    const float4* wr = (const float4*)(fcW + (size_t)o * Hn);
    const float4* hv = (const float4*)hs;
#pragma unroll 8
    for (int k4 = 0; k4 < Hn / 4; ++k4) {
        const float4 w = wr[k4];
        const float4 h = hv[k4];
        acc += w.x * h.x + w.y * h.y + w.z * h.z + w.w * h.w;
    }
    out[(size_t)b * On + o] = sigmf(acc);
}

extern "C" void kernel_launch(void* const* d_in, const int* in_sizes, int n_in,
                              void* d_out, int out_size, void* d_ws, size_t ws_size,
                              hipStream_t stream) {
    (void)in_sizes; (void)n_in; (void)out_size; (void)ws_size;
    const float* x   = (const float*)d_in[0];
    const float* h0i = (const float*)d_in[1];
    const float* c0i = (const float*)d_in[2];
    const float* Wx0 = (const float*)d_in[3];
    const float* Wh0 = (const float*)d_in[4];
    const float* bx0 = (const float*)d_in[5];
    const float* bh0 = (const float*)d_in[6];
    const float* Wx1 = (const float*)d_in[7];
    const float* Wh1 = (const float*)d_in[8];
    const float* bx1 = (const float*)d_in[9];
    const float* bh1 = (const float*)d_in[10];
    const float* fcW = (const float*)d_in[11];
    const float* fcb = (const float*)d_in[12];
    float* out = (float*)d_out;

    char* ws = (char*)d_ws;
    u16* Wpk0   = (u16*)(ws + 0);            // 12,582,912 B
    u16* Wpk1   = (u16*)(ws + 12582912);     // 16,777,216 B
    float* bias = (float*)(ws + 29360128);   // 32,768 B
    u16* h0buf  = (u16*)(ws + 29392896);     // 262,144 B (2 parity slots)
    u16* h1buf  = (u16*)(ws + 29655040);     // 262,144 B
    unsigned* cnt = (unsigned*)(ws + 29917184);

    prep_kernel<<<2048, 256, 0, stream>>>(Wx0, Wh0, bx0, bh0, Wx1, Wh1, bx1, bh1,
                                          h0i, Wpk0, Wpk1, bias, h0buf, h1buf, cnt);

    lstm_persist<<<256, 256, 0, stream>>>(x, Wpk0, Wpk1, bias, c0i, h0buf, h1buf, cnt);

    fc_out<<<64, 256, 0, stream>>>(h1buf + BH, fcW, fcb, out);
}

// Round 5
// 7299.329 us; speedup vs baseline: 3.2095x; 2.4344x over previous
//
#include <hip/hip_runtime.h>
#include <hip/hip_bf16.h>

// LSTM: B=64, S=512, D=512, H=1024, L=2, O=256
// Persistent kernel, fence-FREE cross-XCD coherence:
//   h stores/loads use sc0 sc1 (Infinity-Cache coherent), barrier = relaxed atomics only.
// 256 WGs (128/layer, 8 h-cols each), weights held in VGPRs via volatile-asm loads,
// c-state in registers.

namespace {
constexpr int Bn = 64, Sn = 512, Dn = 512, Hn = 1024, On = 256;
constexpr int BH = Bn * Hn;  // 65536
}

typedef unsigned short u16;
typedef unsigned int u32;
typedef float f32x4 __attribute__((ext_vector_type(4)));
typedef short s16x8 __attribute__((ext_vector_type(8)));

__device__ __forceinline__ u16 f2bf(float f) {
    unsigned int u = __float_as_uint(f);
    unsigned int r = (u + 0x7fffu + ((u >> 16) & 1u)) >> 16;
    return (u16)r;
}
__device__ __forceinline__ float bf2f(u16 b) {
    return __uint_as_float(((unsigned int)b) << 16);
}
__device__ __forceinline__ float sigmf(float x) { return 1.0f / (1.0f + __expf(-x)); }

__device__ __forceinline__ s16x8 cvt8(const float4 a, const float4 b) {
    s16x8 v;
    v[0] = (short)f2bf(a.x); v[1] = (short)f2bf(a.y); v[2] = (short)f2bf(a.z); v[3] = (short)f2bf(a.w);
    v[4] = (short)f2bf(b.x); v[5] = (short)f2bf(b.y); v[6] = (short)f2bf(b.z); v[7] = (short)f2bf(b.w);
    return v;
}

// ---- coherent (Infinity-Cache) access primitives: no cache-maintenance ops ----
__device__ __forceinline__ s16x8 ldg_coh(const u16* p) {
    s16x8 r;
    asm volatile("global_load_dwordx4 %0, %1, off sc0 sc1" : "=&v"(r) : "v"(p) : "memory");
    return r;
}
// plain (L2-cacheable) 16B load as volatile asm: cannot be rematerialized -> result
// stays register-resident for the kernel lifetime
__device__ __forceinline__ s16x8 ldg_pin(const u16* p) {
    s16x8 r;
    asm volatile("global_load_dwordx4 %0, %1, off" : "=&v"(r) : "v"(p) : "memory");
    return r;
}
__device__ __forceinline__ void stg_coh32(u16* p, u32 v) {
    asm volatile("global_store_dword %0, %1, off sc0 sc1" :: "v"(p), "v"(v) : "memory");
}
__device__ __forceinline__ u32 ldg_coh_u32(const u32* p) {
    u32 r;
    asm volatile("global_load_dword %0, %1, off sc0 sc1" : "=&v"(r) : "v"(p) : "memory");
    return r;
}
__device__ __forceinline__ void waitvm0() {
    asm volatile("s_waitcnt vmcnt(0)" ::: "memory");
    __builtin_amdgcn_sched_barrier(0);
}

template <int I> struct IC { static constexpr int v = I; };
template <int N, int I = 0, typename F>
__device__ __forceinline__ void sfor(F&& f) {
    if constexpr (I < N) { f(IC<I>{}); sfor<N, I + 1, F>(static_cast<F&&>(f)); }
}

// ---------------- prep: pack weights into per-wave fragment order ----------------
__global__ void prep_kernel(const float* __restrict__ Wx0, const float* __restrict__ Wh0,
                            const float* __restrict__ bx0, const float* __restrict__ bh0,
                            const float* __restrict__ Wx1, const float* __restrict__ Wh1,
                            const float* __restrict__ bx1, const float* __restrict__ bh1,
                            const float* __restrict__ h0in,
                            u16* __restrict__ Wpk0, u16* __restrict__ Wpk1,
                            float* __restrict__ bcomb,
                            u16* __restrict__ h0buf, u16* __restrict__ h1buf,
                            u32* __restrict__ cnt) {
    const long long idx = (long long)blockIdx.x * 256 + threadIdx.x;
    const long long stride = (long long)gridDim.x * 256;
    if (idx < 8) cnt[idx * 16] = 0u;   // 8 counters, 64B apart

    for (long long i = idx; i < 128LL * 4 * 24 * 512; i += stride) {
        const int j = (int)(i & 7);
        const int lane = (int)((i >> 3) & 63);
        const int f = (int)(i >> 9);
        const int nt = f & 1;
        const int q = f >> 1;
        const int c = q % 12, r = q / 12;
        const int wv = r & 3, wg = r >> 2;
        const int pr = lane & 15, lh = lane >> 4;
        const int row = (nt * 2 + (pr >> 3)) * 1024 + wg * 8 + (pr & 7);
        const int k = (c * 4 + wv) * 32 + lh * 8 + j;
        const float v = (k < 512) ? Wx0[(size_t)row * 512 + k] : Wh0[(size_t)row * 1024 + (k - 512)];
        Wpk0[i] = f2bf(v);
    }
    for (long long i = idx; i < 128LL * 4 * 32 * 512; i += stride) {
        const int j = (int)(i & 7);
        const int lane = (int)((i >> 3) & 63);
        const int f = (int)(i >> 9);
        const int nt = f & 1;
        const int q = f >> 1;
        const int c = q & 15, r = q >> 4;
        const int wv = r & 3, wg = r >> 2;
        const int pr = lane & 15, lh = lane >> 4;
        const int row = (nt * 2 + (pr >> 3)) * 1024 + wg * 8 + (pr & 7);
        const int k = (c * 4 + wv) * 32 + lh * 8 + j;
        const float v = (k < 1024) ? Wx1[(size_t)row * 1024 + k] : Wh1[(size_t)row * 1024 + (k - 1024)];
        Wpk1[i] = f2bf(v);
    }
    for (long long i = idx; i < 4096; i += stride) {
        bcomb[i] = bx0[i] + bh0[i];
        bcomb[4096 + i] = bx1[i] + bh1[i];
    }
    // initial h states live in parity-1 slots
    for (long long i = idx; i < BH; i += stride) {
        h0buf[BH + i] = f2bf(h0in[i]);
        h1buf[BH + i] = f2bf(h0in[BH + i]);
    }
}

// ---------------- fence-free bounded grid barrier ----------------
// All threads: drain own wave's coherent stores, then thread0 arrives + polls 8 counters.
__device__ __forceinline__ void gbar(u32* cbase, int slot, u32 tgt, int* sdead) {
    waitvm0();                 // every wave: h stores acked at coherence point
    __syncthreads();
    if (threadIdx.x == 0 && !*sdead) {
        atomicAdd(cbase + slot * 16, 1u);   // relaxed, device-scope: no fence emission
        int guard = 0;
        for (;;) {
            u32 t0 = ldg_coh_u32(cbase + 0 * 16), t1 = ldg_coh_u32(cbase + 1 * 16);
            u32 t2 = ldg_coh_u32(cbase + 2 * 16), t3 = ldg_coh_u32(cbase + 3 * 16);
            u32 t4 = ldg_coh_u32(cbase + 4 * 16), t5 = ldg_coh_u32(cbase + 5 * 16);
            u32 t6 = ldg_coh_u32(cbase + 6 * 16), t7 = ldg_coh_u32(cbase + 7 * 16);
            waitvm0();
            if (t0 + t1 + t2 + t3 + t4 + t5 + t6 + t7 >= tgt) break;
            __builtin_amdgcn_s_sleep(1);
            if (++guard > (1 << 13)) { *sdead = 1; break; }   // ~ms-scale cap, then latch
        }
    }
    __syncthreads();
}

// ---------------- per-layer persistent loop ----------------
// NC = K/128 chunks (L0:12, L1:16); XC = chunks from first A source (L0: x -> 4, L1: h0 -> 8)
template <int NC, int XC, int LAYER>
__device__ __forceinline__ void run_layer(const float* __restrict__ x,
                                          const u16* __restrict__ Wpk,
                                          const float* __restrict__ bias,
                                          const float* __restrict__ c0in,
                                          u16* h0buf, u16* h1buf,
                                          u32* cnt, int wg, int slot, char* smem, int* sdead) {
    const int tid = threadIdx.x;
    const int wid = tid >> 6, lane = tid & 63;
    const int ln15 = lane & 15, lhi = lane >> 4;
    const int col0 = wg * 8;
    short* As = (short*)smem;     // 2 x [64][128] bf16 A-chunk double buffer
    float* Pf = (float*)smem;     // reused: partials [128][67] f32
    const int m_u = tid & 63, cp_u = tid >> 6;

    // register-resident weights: volatile-asm loads cannot be rematerialized,
    // so the fragments stay live in VGPRs for the whole kernel.
    s16x8 wfr[NC * 2];
    const u16* wbase = Wpk + ((size_t)(wg * 4 + wid) * (NC * 2)) * 512 + lane * 8;
    sfor<NC * 2>([&](auto ff) { wfr[ff.v] = ldg_pin(wbase + (size_t)ff.v * 512); });
    waitvm0();

    float bR[4][2];
#pragma unroll
    for (int g = 0; g < 4; ++g) {
        bR[g][0] = bias[g * 1024 + col0 + cp_u * 2 + 0];
        bR[g][1] = bias[g * 1024 + col0 + cp_u * 2 + 1];
    }
    float cr0 = c0in[(size_t)m_u * 1024 + col0 + cp_u * 2 + 0];
    float cr1 = c0in[(size_t)m_u * 1024 + col0 + cp_u * 2 + 1];

    for (int ph = 0; ph <= 512; ++ph) {
        const bool active = (LAYER == 0) ? (ph < 512) : (ph >= 1);
        if (active) {
            const int t = (LAYER == 0) ? ph : ph - 1;
            const u16* hA = h0buf + (size_t)((ph + 1) & 1) * BH;  // L0: h0 prev ; L1: h0 current-t
            const u16* hB = h1buf + (size_t)(ph & 1) * BH;        // L1 only: h1 prev
            u16* hw = (LAYER == 0) ? h0buf + (size_t)(ph & 1) * BH
                                   : h1buf + (size_t)((ph + 1) & 1) * BH;

            // ---- prologue: stage chunk 0 into buffer 0
            {
                float4 xr[4][2]; s16x8 hr[4];
#pragma unroll
                for (int bb = 0; bb < 4; ++bb) {
                    const int blkid = tid + bb * 256, row = blkid >> 4, cb = blkid & 15;
                    const int kg = cb * 8;
                    if constexpr (LAYER == 0) {
                        const float* sp = x + ((size_t)row * Sn + t) * Dn + kg;
                        xr[bb][0] = *(const float4*)sp; xr[bb][1] = *(const float4*)(sp + 4);
                    } else {
                        hr[bb] = ldg_coh(&hA[(size_t)row * Hn + kg]);
                    }
                }
                waitvm0();
#pragma unroll
                for (int bb = 0; bb < 4; ++bb) {
                    const int blkid = tid + bb * 256, row = blkid >> 4, cb = blkid & 15;
                    s16x8 v;
                    if constexpr (LAYER == 0) v = cvt8(xr[bb][0], xr[bb][1]);
                    else v = hr[bb];
                    *(s16x8*)&As[row * 128 + ((cb ^ (row & 7)) * 8)] = v;
                }
            }
            __syncthreads();

            f32x4 acc[4][2];
#pragma unroll
            for (int mi = 0; mi < 4; ++mi) {
                acc[mi][0] = f32x4{0.f, 0.f, 0.f, 0.f};
                acc[mi][1] = f32x4{0.f, 0.f, 0.f, 0.f};
            }

            sfor<NC>([&](auto cc) {
                constexpr int c = cc.v;
                float4 xr[4][2]; s16x8 hr[4];
                // issue next chunk's loads early (latency hides under MFMA)
                if constexpr (c + 1 < NC) {
                    constexpr int cn = c + 1;
#pragma unroll
                    for (int bb = 0; bb < 4; ++bb) {
                        const int blkid = tid + bb * 256, row = blkid >> 4, cb = blkid & 15;
                        const int kg = cn * 128 + cb * 8;
                        if constexpr (LAYER == 0) {
                            if constexpr (cn < XC) {
                                const float* sp = x + ((size_t)row * Sn + t) * Dn + kg;
                                xr[bb][0] = *(const float4*)sp; xr[bb][1] = *(const float4*)(sp + 4);
                            } else {
                                hr[bb] = ldg_coh(&hA[(size_t)row * Hn + (kg - XC * 128)]);
                            }
                        } else {
                            if constexpr (cn < XC) hr[bb] = ldg_coh(&hA[(size_t)row * Hn + kg]);
                            else hr[bb] = ldg_coh(&hB[(size_t)row * Hn + (kg - XC * 128)]);
                        }
                    }
                }
                // compute chunk c: wave wid handles k-slice (c*4 + wid)
                const int ab = (c & 1) * 8192;
#pragma unroll
                for (int mi = 0; mi < 4; ++mi) {
                    const int arow = mi * 16 + ln15;
                    const s16x8 af =
                        *(const s16x8*)&As[ab + arow * 128 + (((wid * 4 + lhi) ^ (arow & 7)) * 8)];
                    acc[mi][0] = __builtin_amdgcn_mfma_f32_16x16x32_bf16(af, wfr[c * 2 + 0], acc[mi][0], 0, 0, 0);
                    acc[mi][1] = __builtin_amdgcn_mfma_f32_16x16x32_bf16(af, wfr[c * 2 + 1], acc[mi][1], 0, 0, 0);
                }
                // write next chunk into the other buffer (after draining its loads)
                if constexpr (c + 1 < NC) {
                    constexpr int cn = c + 1;
                    const int wb = (cn & 1) * 8192;
                    waitvm0();
#pragma unroll
                    for (int bb = 0; bb < 4; ++bb) {
                        const int blkid = tid + bb * 256, row = blkid >> 4, cb = blkid & 15;
                        s16x8 v;
                        if constexpr (LAYER == 0 && (c + 1) < XC) v = cvt8(xr[bb][0], xr[bb][1]);
                        else v = hr[bb];
                        *(s16x8*)&As[wb + row * 128 + ((cb ^ (row & 7)) * 8)] = v;
                    }
                }
                __syncthreads();
            });

            // ---- cross-wave reduction: partial sums -> LDS
#pragma unroll
            for (int mi = 0; mi < 4; ++mi)
#pragma unroll
                for (int nt = 0; nt < 2; ++nt)
#pragma unroll
                    for (int r = 0; r < 4; ++r) {
                        const int m = mi * 16 + lhi * 4 + r;
                        const int g = nt * 2 + (ln15 >> 3), col = ln15 & 7;
                        Pf[(size_t)((wid * 4 + g) * 8 + col) * 67 + m] = acc[mi][nt][r];
                    }
            __syncthreads();

            // ---- fused cell update: thread owns (m_u, cols col0+2cp_u .. +1)
            float sg[4][2];
#pragma unroll
            for (int g = 0; g < 4; ++g) { sg[g][0] = bR[g][0]; sg[g][1] = bR[g][1]; }
#pragma unroll
            for (int wv = 0; wv < 4; ++wv)
#pragma unroll
                for (int g = 0; g < 4; ++g) {
                    sg[g][0] += Pf[(size_t)(wv * 32 + g * 8 + cp_u * 2 + 0) * 67 + m_u];
                    sg[g][1] += Pf[(size_t)(wv * 32 + g * 8 + cp_u * 2 + 1) * 67 + m_u];
                }
            const float i0 = sigmf(sg[0][0]), f0 = sigmf(sg[1][0]), g0 = tanhf(sg[2][0]), o0 = sigmf(sg[3][0]);
            const float i1 = sigmf(sg[0][1]), f1 = sigmf(sg[1][1]), g1 = tanhf(sg[2][1]), o1 = sigmf(sg[3][1]);
            cr0 = f0 * cr0 + i0 * g0;
            cr1 = f1 * cr1 + i1 * g1;
            const u16 hb0 = f2bf(o0 * tanhf(cr0));
            const u16 hb1 = f2bf(o1 * tanhf(cr1));
            stg_coh32(&hw[(size_t)m_u * Hn + col0 + cp_u * 2], (u32)hb0 | ((u32)hb1 << 16));
        }
        if (ph < 512) gbar(cnt, slot, (u32)(ph + 1) * 256u, sdead);
    }
    waitvm0();   // drain final coherent stores before endpgm
}

__global__ __launch_bounds__(256, 1) void lstm_persist(const float* __restrict__ x,
                                                       const u16* __restrict__ Wpk0,
                                                       const u16* __restrict__ Wpk1,
                                                       const float* __restrict__ bias,
                                                       const float* __restrict__ c0in,
                                                       u16* h0buf, u16* h1buf, u32* cnt) {
    __shared__ __align__(16) char smem[34816];
    __shared__ int sdead;
    if (threadIdx.x == 0) sdead = 0;
    const int slot = blockIdx.x & 7;
    if (blockIdx.x < 128)
        run_layer<12, 4, 0>(x, Wpk0, bias, c0in, h0buf, h1buf, cnt, blockIdx.x, slot, smem, &sdead);
    else
        run_layer<16, 8, 1>(x, Wpk1, bias + 4096, c0in + BH, h0buf, h1buf, cnt, blockIdx.x - 128, slot, smem, &sdead);
}

// ---------------- final FC + sigmoid ----------------
__global__ __launch_bounds__(256) void fc_out(const u16* __restrict__ h1,
                                              const float* __restrict__ fcW,
                                              const float* __restrict__ fcb,
                                              float* __restrict__ out) {
    const int b = blockIdx.x;  // 64
    __shared__ float hs[Hn];
    for (int k = threadIdx.x; k < Hn; k += 256) hs[k] = bf2f(h1[(size_t)b * Hn + k]);
    __syncthreads();
    const int o = threadIdx.x;  // 256
    float acc = fcb[o];
    const float4* wr = (const float4*)(fcW + (size_t)o * Hn);
    const float4* hv = (const float4*)hs;
#pragma unroll 8
    for (int k4 = 0; k4 < Hn / 4; ++k4) {
        const float4 w = wr[k4];
        const float4 h = hv[k4];
        acc += w.x * h.x + w.y * h.y + w.z * h.z + w.w * h.w;
    }
    out[(size_t)b * On + o] = sigmf(acc);
}

extern "C" void kernel_launch(void* const* d_in, const int* in_sizes, int n_in,
                              void* d_out, int out_size, void* d_ws, size_t ws_size,
                              hipStream_t stream) {
    (void)in_sizes; (void)n_in; (void)out_size; (void)ws_size;
    const float* x   = (const float*)d_in[0];
    const float* h0i = (const float*)d_in[1];
    const float* c0i = (const float*)d_in[2];
    const float* Wx0 = (const float*)d_in[3];
    const float* Wh0 = (const float*)d_in[4];
    const float* bx0 = (const float*)d_in[5];
    const float* bh0 = (const float*)d_in[6];
    const float* Wx1 = (const float*)d_in[7];
    const float* Wh1 = (const float*)d_in[8];
    const float* bx1 = (const float*)d_in[9];
    const float* bh1 = (const float*)d_in[10];
    const float* fcW = (const float*)d_in[11];
    const float* fcb = (const float*)d_in[12];
    float* out = (float*)d_out;

    char* ws = (char*)d_ws;
    u16* Wpk0   = (u16*)(ws + 0);            // 12,582,912 B
    u16* Wpk1   = (u16*)(ws + 12582912);     // 16,777,216 B
    float* bias = (float*)(ws + 29360128);   // 32,768 B
    u16* h0buf  = (u16*)(ws + 29392896);     // 262,144 B (2 parity slots)
    u16* h1buf  = (u16*)(ws + 29655040);     // 262,144 B
    u32* cnt    = (u32*)(ws + 29917184);     // 8 counters, 64B apart (512 B)

    prep_kernel<<<2048, 256, 0, stream>>>(Wx0, Wh0, bx0, bh0, Wx1, Wh1, bx1, bh1,
                                          h0i, Wpk0, Wpk1, bias, h0buf, h1buf, cnt);

    lstm_persist<<<256, 256, 0, stream>>>(x, Wpk0, Wpk1, bias, c0i, h0buf, h1buf, cnt);

    fc_out<<<64, 256, 0, stream>>>(h1buf + BH, fcW, fcb, out);
}